// Round 4
// baseline (1838.566 us; speedup 1.0000x reference)
//
#include <hip/hip_runtime.h>
#include <math.h>

#define NPTS 2048
#define NB 8
#define R 2        // rows per thread
#define NW 16      // waves per block
#define BROWS 128  // rows per block
#define NTILE 64   // column tiles of 32 cols
#define TPAIR 16   // col-pairs per tile
#define NRG 16     // row groups per (cloud,b)

typedef float v2f __attribute__((ext_vector_type(2)));
typedef unsigned long long ull;

__device__ __forceinline__ float wexp2(float v) { return __builtin_amdgcn_exp2f(v); }
__device__ __forceinline__ v2f fma2(v2f a, v2f b, v2f c) {
  return __builtin_elementwise_fma(a, b, c);
}
__device__ __forceinline__ v2f max2(v2f a, v2f b) {
  return __builtin_elementwise_max(a, b);
}

__device__ __forceinline__ unsigned quantc(float v) {
  float u = (v + 6.0f) * (127.0f / 12.0f);
  int q = (int)u;
  q = q < 0 ? 0 : (q > 127 ? 127 : q);
  return (unsigned)q;
}
__device__ __forceinline__ unsigned spread3(unsigned v) {
  unsigned r = 0;
#pragma unroll
  for (int i = 0; i < 7; ++i) r |= ((v >> i) & 1u) << (3 * i);
  return r;
}

// ---------------------------------------------------------------------------
// sort: Morton-order each (cloud,b)'s 2048 points; write packed records
// (x,y,z,0.5|p|^2) in sorted order. Also zero potentials and out.
// Sorting is safe: all downstream reductions are permutation-invariant.
// ---------------------------------------------------------------------------
__global__ __launch_bounds__(1024) void emd_sort(const float* __restrict__ x,
                                                 const float* __restrict__ y,
                                                 float4* __restrict__ x4s,
                                                 float4* __restrict__ y4s,
                                                 float* __restrict__ pot0,
                                                 float* __restrict__ out) {
  __shared__ unsigned keys[NPTS];
  int blk = blockIdx.x;            // 0..15
  int cloud = blk >> 3, b = blk & 7;
  const float* src = cloud ? y : x;
  float4* dst = cloud ? y4s : x4s;
  int tid = threadIdx.x;

  for (int i = tid; i < NPTS; i += 1024) {
    int si = (b * NPTS + i) * 3;
    unsigned qx = quantc(src[si]), qy = quantc(src[si + 1]), qz = quantc(src[si + 2]);
    unsigned m = spread3(qx) | (spread3(qy) << 1) | (spread3(qz) << 2);
    keys[i] = (m << 11) | (unsigned)i;
  }
  __syncthreads();
  for (int k = 2; k <= NPTS; k <<= 1) {
    for (int j = k >> 1; j > 0; j >>= 1) {
      for (int i = tid; i < NPTS; i += 1024) {
        int ixj = i ^ j;
        if (ixj > i) {
          unsigned a = keys[i], c2 = keys[ixj];
          bool up = ((i & k) == 0);
          if ((a > c2) == up) { keys[i] = c2; keys[ixj] = a; }
        }
      }
      __syncthreads();
    }
  }
  for (int p = tid; p < NPTS; p += 1024) {
    int id = keys[p] & 2047;
    int si = (b * NPTS + id) * 3;
    float a0 = src[si], a1 = src[si + 1], a2 = src[si + 2];
    dst[b * NPTS + p] = make_float4(a0, a1, a2, 0.5f * (a0 * a0 + a1 * a1 + a2 * a2));
  }
  int gt = blk * 1024 + tid;
  for (int i = gt; i < 2 * NB * NPTS; i += 16 * 1024) {
    pot0[i] = 0.0f;
    pot0[NB * NPTS * 2 + i] = 0.0f;
  }
  if (gt == 0) out[0] = 0.0f;
}

// ---------------------------------------------------------------------------
// meta: static bboxes — per 32-col tile (64 per cloud,b) and per 128-row
// group (16 per cloud,b) — over the SORTED order.
// ---------------------------------------------------------------------------
__global__ __launch_bounds__(256) void emd_meta(const float4* __restrict__ x4s,
                                                const float4* __restrict__ y4s,
                                                float* __restrict__ tilebb,
                                                float* __restrict__ rgbb) {
  int blk = blockIdx.x;            // cloud*8+b
  int cloud = blk >> 3, b = blk & 7;
  const float4* base = (cloud ? y4s : x4s) + b * NPTS;
  int t = threadIdx.x;             // 8 pts each
  float lo0 = 1e30f, lo1 = 1e30f, lo2 = 1e30f;
  float hi0 = -1e30f, hi1 = -1e30f, hi2 = -1e30f;
#pragma unroll
  for (int i = 0; i < 8; ++i) {
    float4 p = base[t * 8 + i];
    lo0 = fminf(lo0, p.x); hi0 = fmaxf(hi0, p.x);
    lo1 = fminf(lo1, p.y); hi1 = fmaxf(hi1, p.y);
    lo2 = fminf(lo2, p.z); hi2 = fmaxf(hi2, p.z);
  }
#pragma unroll
  for (int off = 2; off; off >>= 1) {
    lo0 = fminf(lo0, __shfl_xor(lo0, off)); hi0 = fmaxf(hi0, __shfl_xor(hi0, off));
    lo1 = fminf(lo1, __shfl_xor(lo1, off)); hi1 = fmaxf(hi1, __shfl_xor(hi1, off));
    lo2 = fminf(lo2, __shfl_xor(lo2, off)); hi2 = fmaxf(hi2, __shfl_xor(hi2, off));
  }
  if ((t & 3) == 0) {
    float* o = tilebb + (blk * NTILE + (t >> 2)) * 8;
    o[0] = lo0; o[1] = lo1; o[2] = lo2; o[3] = hi0; o[4] = hi1; o[5] = hi2;
  }
#pragma unroll
  for (int off = 8; off >= 4; off >>= 1) {
    lo0 = fminf(lo0, __shfl_xor(lo0, off)); hi0 = fmaxf(hi0, __shfl_xor(hi0, off));
    lo1 = fminf(lo1, __shfl_xor(lo1, off)); hi1 = fmaxf(hi1, __shfl_xor(hi1, off));
    lo2 = fminf(lo2, __shfl_xor(lo2, off)); hi2 = fmaxf(hi2, __shfl_xor(hi2, off));
  }
  if ((t & 15) == 0) {
    float* o = rgbb + (blk * NRG + (t >> 4)) * 8;
    o[0] = lo0; o[1] = lo1; o[2] = lo2; o[3] = hi0; o[4] = hi1; o[5] = hi2;
  }
}

// ---------------------------------------------------------------------------
// Bootstrap sweep: exact online softmax (first eps, c tiny -> no culling).
// Identical to the proven round-0 kernel, operating on sorted records.
// ---------------------------------------------------------------------------
__global__ __launch_bounds__(1024, 8) void emd_sweep_boot(
    const float4* __restrict__ x4s, const float4* __restrict__ y4s,
    const float* __restrict__ pot_in, float* __restrict__ pot_out,
    float* __restrict__ amax_out, float c, float neg_eps_ln2, float eps_logM) {
  __shared__ union {
    struct { float4 A[NPTS / 2]; float4 B[NPTS / 2]; } cp;
    struct { float m[NW][BROWS]; float l[NW][BROWS]; } mg;
  } sh;

  int blk = blockIdx.x;
  int mat = blk >> 7;
  int b = (blk >> 4) & 7;
  int rg = blk & 15;
  int tid = threadIdx.x;
  int lane = tid & 63;
  int w = tid >> 6;

  const float4* rowp = (mat == 1 || mat == 3) ? y4s : x4s;
  const float4* colp = (mat == 0 || mat == 3) ? y4s : x4s;
  int hidx = (mat < 2) ? (mat ^ 1) : mat;
  const float* h = pot_in + (hidx * NB + b) * NPTS;
  const float4* colb = colp + b * NPTS;

  {
    float4 q0 = colb[2 * tid];
    float4 q1 = colb[2 * tid + 1];
    float2 hv = ((const float2*)h)[tid];
    sh.cp.A[tid] = make_float4(q0.x, q1.x, q0.y, q1.y);
    sh.cp.B[tid] = make_float4(q0.z, q1.z, (hv.x - q0.w) * c, (hv.y - q1.w) * c);
  }
  __syncthreads();

  int rowbase = rg * BROWS;
  const float4* rowb = rowp + b * NPTS + rowbase;

  v2f xs0[R], xs1[R], xs2[R];
  float m[R], l[R];
#pragma unroll
  for (int r = 0; r < R; ++r) {
    float4 p = rowb[r * 64 + lane];
    float a0 = p.x * c, a1 = p.y * c, a2 = p.z * c;
    xs0[r] = (v2f){a0, a0};
    xs1[r] = (v2f){a1, a1};
    xs2[r] = (v2f){a2, a2};
    m[r] = -INFINITY;
    l[r] = 0.0f;
  }

  int p0 = w * 64;
  for (int tp = 0; tp < 64; tp += 4) {
    float4 A[4], B[4];
#pragma unroll
    for (int j = 0; j < 4; ++j) {
      A[j] = sh.cp.A[p0 + tp + j];
      B[j] = sh.cp.B[p0 + tp + j];
    }
#pragma unroll
    for (int r = 0; r < R; ++r) {
      v2f s2[4];
#pragma unroll
      for (int j = 0; j < 4; ++j) {
        v2f qx = {A[j].x, A[j].y};
        v2f qy = {A[j].z, A[j].w};
        v2f qz = {B[j].x, B[j].y};
        v2f qw = {B[j].z, B[j].w};
        s2[j] = fma2(xs0[r], qx, fma2(xs1[r], qy, fma2(xs2[r], qz, qw)));
      }
      v2f t0 = max2(s2[0], s2[1]);
      v2f t1 = max2(s2[2], s2[3]);
      v2f u = max2(t0, t1);
      float mt = fmaxf(u.x, u.y);
      float mn = fmaxf(m[r], mt);
      v2f mn2 = {mn, mn};
      v2f acc = {0.0f, 0.0f};
#pragma unroll
      for (int j = 0; j < 4; ++j) {
        v2f d = s2[j] - mn2;
        v2f e;
        e.x = wexp2(d.x);
        e.y = wexp2(d.y);
        acc += e;
      }
      float er = wexp2(m[r] - mn);
      l[r] = fmaf(l[r], er, acc.x + acc.y);
      m[r] = mn;
    }
  }

  __syncthreads();
#pragma unroll
  for (int r = 0; r < R; ++r) {
    sh.mg.m[w][r * 64 + lane] = m[r];
    sh.mg.l[w][r * 64 + lane] = l[r];
  }
  __syncthreads();

  if (w < 2) {
    int row = w * 64 + lane;
    float M = sh.mg.m[0][row];
#pragma unroll
    for (int q = 1; q < NW; ++q) M = fmaxf(M, sh.mg.m[q][row]);
    float L = 0.0f;
#pragma unroll
    for (int q = 0; q < NW; ++q)
      L += sh.mg.l[q][row] * wexp2(sh.mg.m[q][row] - M);
    float pw = rowb[row].w;
    float res = pw + neg_eps_ln2 * (M + log2f(L)) + eps_logM;
    float invc = -neg_eps_ln2;
    amax_out[(mat * NB + b) * NPTS + rowbase + row] = M * invc;
    const float* oldp = pot_in + (mat * NB + b) * NPTS + rowbase;
    float* outp = pot_out + (mat * NB + b) * NPTS + rowbase;
    outp[row] = 0.5f * (oldp[row] + res);
  }
}

// ---------------------------------------------------------------------------
// Fixed-reference sweep WITH exact tile culling. Tile bound (conservative):
//   d_max(tile) <= c*max_bbox(x.q) + max_tile(qw) - c*min_rows(mref)
// Tiles with bound < -64 contribute < 2^-53 relative to L (>= 2^-11) and are
// skipped exactly (swamped below fp32 ulp). Survivors distributed round-robin
// over the 16 waves. Every row's dominant tile satisfies
// bound >= true_max_row - mref_min >= -11, so it is never culled.
// ---------------------------------------------------------------------------
template <bool FINAL>
__global__ __launch_bounds__(1024, 8) void emd_sweep_ref(
    const float4* __restrict__ x4s, const float4* __restrict__ y4s,
    const float* __restrict__ pot_in, float* __restrict__ pot_out,
    const float* __restrict__ amax_in, float* __restrict__ amax_out,
    const float* __restrict__ tilebb, const float* __restrict__ rgbb,
    float* __restrict__ out, float c, float neg_eps_ln2, float eps_logM) {
  __shared__ union {
    struct { float4 A[NPTS / 2]; float4 B[NPTS / 2]; } cp;
    float lbuf[NW][BROWS];
  } sh;
  __shared__ float Wt[NTILE];
  __shared__ float wmin[NW];
  __shared__ ull smask;

  int blk = blockIdx.x;
  int mat = blk >> 7;
  int b = (blk >> 4) & 7;
  int rg = blk & 15;
  int tid = threadIdx.x;
  int lane = tid & 63;
  int w = tid >> 6;

  int cr = (mat == 1 || mat == 3) ? 1 : 0;
  int cc = (mat == 0 || mat == 3) ? 1 : 0;
  const float4* rowp = cr ? y4s : x4s;
  const float4* colp = cc ? y4s : x4s;
  int hidx = (mat < 2) ? (mat ^ 1) : mat;
  const float* h = pot_in + (hidx * NB + b) * NPTS;
  const float4* colb = colp + b * NPTS;

  {
    float4 q0 = colb[2 * tid];
    float4 q1 = colb[2 * tid + 1];
    float2 hv = ((const float2*)h)[tid];
    float qwx = (hv.x - q0.w) * c, qwy = (hv.y - q1.w) * c;
    sh.cp.A[tid] = make_float4(q0.x, q1.x, q0.y, q1.y);
    sh.cp.B[tid] = make_float4(q0.z, q1.z, qwx, qwy);
    float wq = fmaxf(qwx, qwy);
#pragma unroll
    for (int off = 8; off; off >>= 1) wq = fmaxf(wq, __shfl_xor(wq, off));
    if ((tid & 15) == 0) Wt[tid >> 4] = wq;   // tile = pair>>4
  }

  int rowbase = rg * BROWS;
  const float4* rowb = rowp + b * NPTS + rowbase;
  const float* amrow = amax_in + (mat * NB + b) * NPTS + rowbase;

  v2f xs0[R], xs1[R], xs2[R], mref2[R], acc[R];
  float amn = 1e30f;
#pragma unroll
  for (int r = 0; r < R; ++r) {
    float4 p = rowb[r * 64 + lane];
    float a0 = p.x * c, a1 = p.y * c, a2 = p.z * c;
    xs0[r] = (v2f){a0, a0};
    xs1[r] = (v2f){a1, a1};
    xs2[r] = (v2f){a2, a2};
    float am = amrow[r * 64 + lane];
    amn = fminf(amn, am);
    float mr = am * c;
    mref2[r] = (v2f){mr, mr};
    acc[r] = (v2f){0.0f, 0.0f};
  }
#pragma unroll
  for (int off = 32; off; off >>= 1) amn = fminf(amn, __shfl_xor(amn, off));
  if (lane == 0) wmin[w] = amn;
  __syncthreads();

  if (w == 0) {
    float a2 = wmin[0];
#pragma unroll
    for (int q = 1; q < NW; ++q) a2 = fminf(a2, wmin[q]);
    const float* rb = rgbb + ((cr * NB + b) * NRG + rg) * 8;
    float rl0 = rb[0], rl1 = rb[1], rl2 = rb[2];
    float rh0 = rb[3], rh1 = rb[4], rh2 = rb[5];
    const float* tb = tilebb + ((cc * NB + b) * NTILE + lane) * 8;
    float t0 = tb[0], t1 = tb[1], t2 = tb[2], t3 = tb[3], t4 = tb[4], t5 = tb[5];
    float dm = fmaxf(fmaxf(rl0 * t0, rl0 * t3), fmaxf(rh0 * t0, rh0 * t3)) +
               fmaxf(fmaxf(rl1 * t1, rl1 * t4), fmaxf(rh1 * t1, rh1 * t4)) +
               fmaxf(fmaxf(rl2 * t2, rl2 * t5), fmaxf(rh2 * t2, rh2 * t5));
    float bound = fmaf(c, dm, Wt[lane]) - a2 * c;
    ull bal = __ballot(bound >= -64.0f);
    if (lane == 0) smask = bal;
  }
  __syncthreads();
  ull mask = smask;

  int ord = 0;
  for (int t = 0; t < NTILE; ++t) {
    if (!((mask >> t) & 1)) continue;
    if ((ord++ & 15) != w) continue;
    int pb = t * TPAIR;
#pragma unroll
    for (int ii = 0; ii < 4; ++ii) {
      int p0 = pb + ii * 4;
      float4 A[4], B[4];
#pragma unroll
      for (int j = 0; j < 4; ++j) {
        A[j] = sh.cp.A[p0 + j];
        B[j] = sh.cp.B[p0 + j];
      }
#pragma unroll
      for (int r = 0; r < R; ++r) {
#pragma unroll
        for (int j = 0; j < 4; ++j) {
          v2f qx = {A[j].x, A[j].y};
          v2f qy = {A[j].z, A[j].w};
          v2f qz = {B[j].x, B[j].y};
          v2f qw = {B[j].z, B[j].w};
          v2f s2 = fma2(xs0[r], qx, fma2(xs1[r], qy, fma2(xs2[r], qz, qw)));
          v2f d = s2 - mref2[r];
          v2f e;
          e.x = wexp2(d.x);
          e.y = wexp2(d.y);
          acc[r] += e;
        }
      }
    }
  }

  __syncthreads();  // colpack dead; safe to overwrite (union)
#pragma unroll
  for (int r = 0; r < R; ++r)
    sh.lbuf[w][r * 64 + lane] = acc[r].x + acc[r].y;
  __syncthreads();

  if (w < 2) {
    int row = w * 64 + lane;
    float L = sh.lbuf[0][row];
#pragma unroll
    for (int q = 1; q < NW; ++q) L += sh.lbuf[q][row];
    float mr = amrow[row] * c;
    float lse = mr + log2f(L);
    float pw = rowb[row].w;
    float res = pw + neg_eps_ln2 * lse + eps_logM;
    float invc = -neg_eps_ln2;
    if (FINAL) {
      float sign = (mat < 2) ? 1.0f : -1.0f;
      float val = sign * res * (1.0f / (float)(NB * NPTS));
#pragma unroll
      for (int off = 32; off; off >>= 1) val += __shfl_xor(val, off);
      if (lane == 0) atomicAdd(out, val);
    } else {
      amax_out[(mat * NB + b) * NPTS + rowbase + row] = lse * invc;
      const float* oldp = pot_in + (mat * NB + b) * NPTS + rowbase;
      float* outp = pot_out + (mat * NB + b) * NPTS + rowbase;
      outp[row] = 0.5f * (oldp[row] + res);
    }
  }
}

// ---------------------------------------------------------------------------
extern "C" void kernel_launch(void* const* d_in, const int* in_sizes, int n_in,
                              void* d_out, int out_size, void* d_ws, size_t ws_size,
                              hipStream_t stream) {
  const float* x = (const float*)d_in[0];
  const float* y = (const float*)d_in[1];
  float* out = (float*)d_out;

  char* ws = (char*)d_ws;
  float4* x4s = (float4*)ws;                       // 256 KB
  float4* y4s = (float4*)(ws + 262144);            // 256 KB
  float* pot = (float*)(ws + 524288);              // 512 KB (2 buffers)
  float* amax = (float*)(ws + 1048576);            // 256 KB
  float* tilebb = (float*)(ws + 1310720);          // 32 KB (16*64*8 floats)
  float* rgbb = (float*)(ws + 1343488);            // 8 KB  (16*16*8 floats)

  emd_sort<<<16, 1024, 0, stream>>>(x, y, x4s, y4s, pot, out);
  emd_meta<<<16, 256, 0, stream>>>(x4s, y4s, tilebb, rgbb);

  // eps schedule: s=8.0, *=0.9 while s>0.01; eps = f32(s)^2; append 0.01^2
  float eps_arr[80];
  int ne = 0;
  double s = 8.0;
  while (s > 0.01) {
    float sf = (float)s;
    eps_arr[ne++] = sf * sf;
    s *= 0.9;
  }
  {
    float bf = 0.01f;
    eps_arr[ne++] = bf * bf;
  }

  const double LOG2E = 1.4426950408889634;
  const double LN2 = 0.6931471805599453;
  const double LOG2048 = 7.624618986159398;

  int cur = 0;
  for (int k = 0; k < ne; ++k) {
    float eps = eps_arr[k];
    float c = (float)(LOG2E / (double)eps);
    float nel = (float)(-(double)eps * LN2);
    float elM = (float)((double)eps * LOG2048);
    if (k == 0) {
      emd_sweep_boot<<<512, 1024, 0, stream>>>(x4s, y4s, pot + cur * 65536,
                                               pot + (1 - cur) * 65536, amax,
                                               c, nel, elM);
    } else {
      emd_sweep_ref<false><<<512, 1024, 0, stream>>>(
          x4s, y4s, pot + cur * 65536, pot + (1 - cur) * 65536, amax, amax,
          tilebb, rgbb, out, c, nel, elM);
    }
    cur ^= 1;
  }

  {
    float eps = eps_arr[ne - 1];
    float c = (float)(LOG2E / (double)eps);
    float nel = (float)(-(double)eps * LN2);
    float elM = (float)((double)eps * LOG2048);
    emd_sweep_ref<true><<<512, 1024, 0, stream>>>(
        x4s, y4s, pot + cur * 65536, nullptr, amax, nullptr, tilebb, rgbb,
        out, c, nel, elM);
  }
}